// Round 4
// baseline (210.689 us; speedup 1.0000x reference)
//
#include <hip/hip_runtime.h>

#define B_DIM 4096
#define I_DIM 1024
#define O_DIM 1024
#define ON_DIM 4096   // O * N fan-in columns

typedef _Float16 half8  __attribute__((ext_vector_type(8)));
typedef _Float16 half4_t __attribute__((ext_vector_type(4)));
typedef float    floatx4 __attribute__((ext_vector_type(4)));

// ---------------------------------------------------------------------------
// Kernel 1 (fused prep):
//  blocks [0,1024):   softmax of mapping_logits rows -> fp16 weights (wave/row)
//  blocks [1024,2048): x fp32 -> fp16 convert
// ---------------------------------------------------------------------------
__global__ __launch_bounds__(256)
void ltn_prep(const float* __restrict__ logits, const float* __restrict__ x,
              _Float16* __restrict__ wh, _Float16* __restrict__ xh) {
  const int t = threadIdx.x, lane = t & 63, wv = t >> 6;
  if (blockIdx.x < 1024) {
    const int row = blockIdx.x * 4 + wv;
    const float4* src = (const float4*)(logits + (size_t)row * I_DIM);
    float4 v[4];
#pragma unroll
    for (int j = 0; j < 4; j++) v[j] = src[j * 64 + lane];
    float m = -1e30f;
#pragma unroll
    for (int j = 0; j < 4; j++)
      m = fmaxf(m, fmaxf(fmaxf(v[j].x, v[j].y), fmaxf(v[j].z, v[j].w)));
#pragma unroll
    for (int off = 1; off < 64; off <<= 1) m = fmaxf(m, __shfl_xor(m, off));
    float e[16];
    float s = 0.0f;
#pragma unroll
    for (int j = 0; j < 4; j++) {
      e[4 * j + 0] = __expf(v[j].x - m);
      e[4 * j + 1] = __expf(v[j].y - m);
      e[4 * j + 2] = __expf(v[j].z - m);
      e[4 * j + 3] = __expf(v[j].w - m);
      s += (e[4 * j + 0] + e[4 * j + 1]) + (e[4 * j + 2] + e[4 * j + 3]);
    }
#pragma unroll
    for (int off = 1; off < 64; off <<= 1) s += __shfl_xor(s, off);
    const float inv = 1.0f / s;
    half4_t* dst = (half4_t*)(wh + (size_t)row * I_DIM);
#pragma unroll
    for (int j = 0; j < 4; j++) {
      half4_t h;
      h[0] = (_Float16)(e[4 * j + 0] * inv);
      h[1] = (_Float16)(e[4 * j + 1] * inv);
      h[2] = (_Float16)(e[4 * j + 2] * inv);
      h[3] = (_Float16)(e[4 * j + 3] * inv);
      dst[j * 64 + lane] = h;
    }
  } else {
    const int cidx = blockIdx.x - 1024;
    const float4* src = (const float4*)x;
    half4_t* dst = (half4_t*)xh;
#pragma unroll
    for (int j = 0; j < 4; j++) {
      const int idx = cidx * 1024 + j * 256 + t;
      const float4 v = src[idx];
      half4_t h;
      h[0] = (_Float16)v.x; h[1] = (_Float16)v.y;
      h[2] = (_Float16)v.z; h[3] = (_Float16)v.w;
      dst[idx] = h;
    }
  }
}

// ---------------------------------------------------------------------------
// Kernel 2: fused GEMM + sigmoid + 16-corner LUT interp — BARRIER-FREE.
// Both operands are K-major, so the 16x16x32 fragment (row = lane&15,
// k = (lane>>4)*8 + j) is a natively loadable global half8: no LDS, no
// __syncthreads, no vmcnt(0) drains. One-panel-ahead register prefetch;
// the compiler emits fine-grained vmcnt waits and ~3 wave-sets/SIMD slip
// freely to hide L2 latency. 128x128 block = 4 waves (2x2), each 64x64.
// ---------------------------------------------------------------------------
__global__ __launch_bounds__(256)
void ltn_gemm_lut(const _Float16* __restrict__ xh,   // [B][I]
                  const _Float16* __restrict__ wh,   // [ON][I]
                  const float* __restrict__ lut,     // [O][16]
                  float* __restrict__ out) {         // [B][O]
  const int tid  = threadIdx.x;
  const int lane = tid & 63;
  const int wv   = tid >> 6;
  const int wr   = wv >> 1;      // wave row (0..1)
  const int wc   = wv & 1;       // wave col (0..1)
  const int bm0  = blockIdx.x * 128;
  const int bn0  = blockIdx.y * 128;
  const int fm   = lane & 15;    // m/n within a 16-tile
  const int kq   = lane >> 4;    // k-chunk: k = kq*8 + j

  // per-fragment base pointers (advance by k only)
  const half8* pa[4];
  const half8* pb[4];
#pragma unroll
  for (int f = 0; f < 4; f++) {
    pa[f] = (const half8*)(xh + (size_t)(bm0 + wr * 64 + f * 16 + fm) * I_DIM + kq * 8);
    pb[f] = (const half8*)(wh + (size_t)(bn0 + wc * 64 + f * 16 + fm) * I_DIM + kq * 8);
  }
  // pointer step per 32-k panel: 32 halfs = 4 half8
  floatx4 acc[4][4];
#pragma unroll
  for (int i = 0; i < 4; i++)
#pragma unroll
    for (int j = 0; j < 4; j++) acc[i][j] = (floatx4)0.0f;

  half8 ac[4], bc[4], an[4], bn[4];
#pragma unroll
  for (int f = 0; f < 4; f++) { ac[f] = pa[f][0]; bc[f] = pb[f][0]; }

  // panels 0..31; preloaded 0; pairs (1,2),(3,4)...(29,30); tail 31
  for (int p = 1; p < 31; p += 2) {
#pragma unroll
    for (int f = 0; f < 4; f++) { an[f] = pa[f][p * 4]; bn[f] = pb[f][p * 4]; }
#pragma unroll
    for (int mt = 0; mt < 4; mt++)
#pragma unroll
      for (int nt = 0; nt < 4; nt++)
        acc[mt][nt] = __builtin_amdgcn_mfma_f32_16x16x32_f16(
            ac[mt], bc[nt], acc[mt][nt], 0, 0, 0);
#pragma unroll
    for (int f = 0; f < 4; f++) { ac[f] = pa[f][(p + 1) * 4]; bc[f] = pb[f][(p + 1) * 4]; }
#pragma unroll
    for (int mt = 0; mt < 4; mt++)
#pragma unroll
      for (int nt = 0; nt < 4; nt++)
        acc[mt][nt] = __builtin_amdgcn_mfma_f32_16x16x32_f16(
            an[mt], bn[nt], acc[mt][nt], 0, 0, 0);
  }
  // tail: panel 31 then compute 30 (in ac) and 31
#pragma unroll
  for (int f = 0; f < 4; f++) { an[f] = pa[f][31 * 4]; bn[f] = pb[f][31 * 4]; }
#pragma unroll
  for (int mt = 0; mt < 4; mt++)
#pragma unroll
    for (int nt = 0; nt < 4; nt++)
      acc[mt][nt] = __builtin_amdgcn_mfma_f32_16x16x32_f16(
          ac[mt], bc[nt], acc[mt][nt], 0, 0, 0);
#pragma unroll
  for (int mt = 0; mt < 4; mt++)
#pragma unroll
    for (int nt = 0; nt < 4; nt++)
      acc[mt][nt] = __builtin_amdgcn_mfma_f32_16x16x32_f16(
          an[mt], bn[nt], acc[mt][nt], 0, 0, 0);

  // ---- fused epilogue: sigmoid -> gather 4 fan-in values -> LUT contraction
  // C/D layout: col = lane&15, row = (lane>>4)*4 + reg. The 4 n-values of one
  // o live in 4 consecutive lanes (same row, cols o*4..o*4+3).
#pragma unroll
  for (int nt = 0; nt < 4; nt++) {
    const int o = (bn0 + wc * 64 + nt * 16 + (lane & 15)) >> 2;
    const float4* lt4 = (const float4*)(lut + (size_t)o * 16);
    const float4 L0 = lt4[0], L1 = lt4[1], L2 = lt4[2], L3 = lt4[3];
#pragma unroll
    for (int mt = 0; mt < 4; mt++) {
#pragma unroll
      for (int r = 0; r < 4; r++) {
        const float v  = acc[mt][nt][r];
        const float sv = 1.0f / (1.0f + __expf(-v));
        const float s1 = __shfl_down(sv, 1);
        const float s2 = __shfl_down(sv, 2);
        const float s3 = __shfl_down(sv, 3);
        if ((lane & 3) == 0) {
          const float s0 = sv;
          const float a0 = L0.x + (L2.x - L0.x) * s3;
          const float a1 = L0.y + (L2.y - L0.y) * s3;
          const float a2 = L0.z + (L2.z - L0.z) * s3;
          const float a3 = L0.w + (L2.w - L0.w) * s3;
          const float a4 = L1.x + (L3.x - L1.x) * s3;
          const float a5 = L1.y + (L3.y - L1.y) * s3;
          const float a6 = L1.z + (L3.z - L1.z) * s3;
          const float a7 = L1.w + (L3.w - L1.w) * s3;
          const float b0 = a0 + (a4 - a0) * s2;
          const float b1 = a1 + (a5 - a1) * s2;
          const float b2 = a2 + (a6 - a2) * s2;
          const float b3 = a3 + (a7 - a3) * s2;
          const float c0 = b0 + (b2 - b0) * s1;
          const float c1 = b1 + (b3 - b1) * s1;
          const float res = c0 + (c1 - c0) * s0;
          const int row = bm0 + wr * 64 + mt * 16 + (lane >> 4) * 4 + r;
          out[(size_t)row * O_DIM + o] = res;
        }
      }
    }
  }
}

// ---------------------------------------------------------------------------
extern "C" void kernel_launch(void* const* d_in, const int* in_sizes, int n_in,
                              void* d_out, int out_size, void* d_ws, size_t ws_size,
                              hipStream_t stream) {
  const float* x      = (const float*)d_in[0];  // (B, I)
  const float* logits = (const float*)d_in[1];  // (O, N, I)
  const float* lut    = (const float*)d_in[2];  // (O, 16)
  float* out          = (float*)d_out;          // (B, O)

  _Float16* wh = (_Float16*)d_ws;                                  // 8 MB
  _Float16* xh = (_Float16*)d_ws + (size_t)ON_DIM * I_DIM;         // 8 MB

  ltn_prep<<<2048, 256, 0, stream>>>(logits, x, wh, xh);
  dim3 grid(B_DIM / 128, ON_DIM / 128);
  ltn_gemm_lut<<<grid, 256, 0, stream>>>(xh, wh, lut, out);
}

// Round 5
// 184.387 us; speedup vs baseline: 1.1426x; 1.1426x over previous
//
#include <hip/hip_runtime.h>

#define B_DIM 4096
#define I_DIM 1024
#define O_DIM 1024
#define ON_DIM 4096   // O * N fan-in columns

typedef _Float16 half8  __attribute__((ext_vector_type(8)));
typedef _Float16 half4_t __attribute__((ext_vector_type(4)));
typedef float    floatx4 __attribute__((ext_vector_type(4)));

// ---------------------------------------------------------------------------
// Kernel 1 (fused prep):
//  blocks [0,1024):   softmax of mapping_logits rows -> fp16 weights (wave/row)
//  blocks [1024,2048): x fp32 -> fp16 convert
// ---------------------------------------------------------------------------
__global__ __launch_bounds__(256)
void ltn_prep(const float* __restrict__ logits, const float* __restrict__ x,
              _Float16* __restrict__ wh, _Float16* __restrict__ xh) {
  const int t = threadIdx.x, lane = t & 63, wv = t >> 6;
  if (blockIdx.x < 1024) {
    const int row = blockIdx.x * 4 + wv;
    const float4* src = (const float4*)(logits + (size_t)row * I_DIM);
    float4 v[4];
#pragma unroll
    for (int j = 0; j < 4; j++) v[j] = src[j * 64 + lane];
    float m = -1e30f;
#pragma unroll
    for (int j = 0; j < 4; j++)
      m = fmaxf(m, fmaxf(fmaxf(v[j].x, v[j].y), fmaxf(v[j].z, v[j].w)));
#pragma unroll
    for (int off = 1; off < 64; off <<= 1) m = fmaxf(m, __shfl_xor(m, off));
    float e[16];
    float s = 0.0f;
#pragma unroll
    for (int j = 0; j < 4; j++) {
      e[4 * j + 0] = __expf(v[j].x - m);
      e[4 * j + 1] = __expf(v[j].y - m);
      e[4 * j + 2] = __expf(v[j].z - m);
      e[4 * j + 3] = __expf(v[j].w - m);
      s += (e[4 * j + 0] + e[4 * j + 1]) + (e[4 * j + 2] + e[4 * j + 3]);
    }
#pragma unroll
    for (int off = 1; off < 64; off <<= 1) s += __shfl_xor(s, off);
    const float inv = 1.0f / s;
    half4_t* dst = (half4_t*)(wh + (size_t)row * I_DIM);
#pragma unroll
    for (int j = 0; j < 4; j++) {
      half4_t h;
      h[0] = (_Float16)(e[4 * j + 0] * inv);
      h[1] = (_Float16)(e[4 * j + 1] * inv);
      h[2] = (_Float16)(e[4 * j + 2] * inv);
      h[3] = (_Float16)(e[4 * j + 3] * inv);
      dst[j * 64 + lane] = h;
    }
  } else {
    const int cidx = blockIdx.x - 1024;
    const float4* src = (const float4*)x;
    half4_t* dst = (half4_t*)xh;
#pragma unroll
    for (int j = 0; j < 4; j++) {
      const int idx = cidx * 1024 + j * 256 + t;
      const float4 v = src[idx];
      half4_t h;
      h[0] = (_Float16)v.x; h[1] = (_Float16)v.y;
      h[2] = (_Float16)v.z; h[3] = (_Float16)v.w;
      dst[idx] = h;
    }
  }
}

// ---------------------------------------------------------------------------
// Kernel 2: fused GEMM + LUT — WAVE-SPECIALIZED producer/consumer.
// 5 waves: waves 0..3 compute a 128x128 tile (each 64x64 = 4x4 MFMA 16x16x32),
// wave 4 streams A+B 32-k tiles into a 4-slot LDS ring via global_load_lds,
// pacing with s_waitcnt vmcnt(32) (waits slot i-2 only — NEVER vmcnt(0), so
// 32..48 KB stays in flight continuously). Sync = monotone LDS flags:
//   ready[s]: producer publishes token i+1 after slot s holds iter i's tiles
//   done[s]:  each consumer wave +1 per use; producer reuses at done==4*round
// No __syncthreads in the K-loop -> no queue drain (the R1-R3 bottleneck:
// block-iter was 1760 cyc vs 256 cyc of MFMA = the measured 14.5% MfmaUtil).
// ---------------------------------------------------------------------------
__global__ __launch_bounds__(320)
void ltn_gemm_lut(const _Float16* __restrict__ xh,   // [B][I]
                  const _Float16* __restrict__ wh,   // [ON][I]
                  const float* __restrict__ lut,     // [O][16]
                  float* __restrict__ out) {         // [B][O]
  // ring[slot][mat][kb][m][8]: mat 0=A 1=B, 8KB each; slot = 16KB; total 64KB
  __shared__ _Float16 ring[4][2][4][128][8];
  __shared__ int readyv[4];
  __shared__ int donev[4];

  const int tid  = threadIdx.x;
  const int lane = tid & 63;
  const int wv   = tid >> 6;     // 0..3 consumers, 4 producer
  const int bm0  = blockIdx.x * 128;
  const int bn0  = blockIdx.y * 128;

  if (tid < 4) { readyv[tid] = 0; donev[tid] = 0; }
  __syncthreads();               // only barrier in the kernel

  if (wv == 4) {
    // ---------------- producer ----------------
    const _Float16* rowA0 = xh + (size_t)(bm0 + lane) * I_DIM;
    const _Float16* rowA1 = rowA0 + (size_t)64 * I_DIM;
    const _Float16* rowB0 = wh + (size_t)(bn0 + lane) * I_DIM;
    const _Float16* rowB1 = rowB0 + (size_t)64 * I_DIM;
    volatile int* dv = donev;
    volatile int* rv = readyv;
#pragma unroll 4
    for (int i = 0; i < 32; i++) {
      const int s = i & 3;
      if (i >= 4) {                       // slot reuse: consumers done?
        const int need = (i >> 2) * 4;
        while (dv[s] < need) __builtin_amdgcn_s_sleep(1);
      }
      asm volatile("" ::: "memory");
      const int k0 = i * 32;
      char* lA = (char*)&ring[s][0][0][0][0];
      char* lB = (char*)&ring[s][1][0][0][0];
#pragma unroll
      for (int j = 0; j < 8; j++) {       // A: 8KB = 8 x 1KB GLL
        const _Float16* gA = ((j & 1) ? rowA1 : rowA0) + k0 + (j >> 1) * 8;
        __builtin_amdgcn_global_load_lds(
            (const __attribute__((address_space(1))) void*)gA,
            (__attribute__((address_space(3))) void*)(lA + j * 1024), 16, 0, 0);
      }
#pragma unroll
      for (int j = 0; j < 8; j++) {       // B: 8KB
        const _Float16* gB = ((j & 1) ? rowB1 : rowB0) + k0 + (j >> 1) * 8;
        __builtin_amdgcn_global_load_lds(
            (const __attribute__((address_space(1))) void*)gB,
            (__attribute__((address_space(3))) void*)(lB + j * 1024), 16, 0, 0);
      }
      if (i >= 2) {                       // slot i-2 complete (<=32 left in Q)
        asm volatile("s_waitcnt vmcnt(32)" ::: "memory");
        if (lane == 0) rv[(i - 2) & 3] = i - 1;   // token (i-2)+1
      }
    }
    asm volatile("s_waitcnt vmcnt(16)" ::: "memory");
    if (lane == 0) rv[2] = 31;
    asm volatile("s_waitcnt vmcnt(0)" ::: "memory");
    if (lane == 0) rv[3] = 32;
  } else {
    // ---------------- consumers ----------------
    const int wr = wv >> 1;      // wave row (0..1)
    const int wc = wv & 1;       // wave col (0..1)
    const int fm = lane & 15;
    const int kq = lane >> 4;
    volatile int* rv = readyv;

    floatx4 acc[4][4];
#pragma unroll
    for (int i = 0; i < 4; i++)
#pragma unroll
      for (int j = 0; j < 4; j++) acc[i][j] = (floatx4)0.0f;

    for (int io = 0; io < 32; io += 4) {
#pragma unroll
      for (int s = 0; s < 4; s++) {
        const int i = io + s;
        while (rv[s] < i + 1) { /* spin */ }
        asm volatile("" ::: "memory");
        half8 af[4], bf[4];
#pragma unroll
        for (int f = 0; f < 4; f++) {
          af[f] = *(const half8*)&ring[s][0][kq][wr * 64 + f * 16 + fm][0];
          bf[f] = *(const half8*)&ring[s][1][kq][wc * 64 + f * 16 + fm][0];
        }
#pragma unroll
        for (int mt = 0; mt < 4; mt++)
#pragma unroll
          for (int nt = 0; nt < 4; nt++)
            acc[mt][nt] = __builtin_amdgcn_mfma_f32_16x16x32_f16(
                af[mt], bf[nt], acc[mt][nt], 0, 0, 0);
        asm volatile("" ::: "memory");
        if (lane == 0) atomicAdd(&donev[s], 1);
      }
    }

    // ---- fused epilogue: sigmoid -> gather 4 fan-in -> LUT contraction
    // C/D layout: col = lane&15, row = (lane>>4)*4 + reg.
#pragma unroll
    for (int nt = 0; nt < 4; nt++) {
      const int o = (bn0 + wc * 64 + nt * 16 + (lane & 15)) >> 2;
      const float4* lt4 = (const float4*)(lut + (size_t)o * 16);
      const float4 L0 = lt4[0], L1 = lt4[1], L2 = lt4[2], L3 = lt4[3];
#pragma unroll
      for (int mt = 0; mt < 4; mt++) {
#pragma unroll
        for (int r = 0; r < 4; r++) {
          const float v  = acc[mt][nt][r];
          const float sv = 1.0f / (1.0f + __expf(-v));
          const float s1 = __shfl_down(sv, 1);
          const float s2 = __shfl_down(sv, 2);
          const float s3 = __shfl_down(sv, 3);
          if ((lane & 3) == 0) {
            const float s0 = sv;
            const float a0 = L0.x + (L2.x - L0.x) * s3;
            const float a1 = L0.y + (L2.y - L0.y) * s3;
            const float a2 = L0.z + (L2.z - L0.z) * s3;
            const float a3 = L0.w + (L2.w - L0.w) * s3;
            const float a4 = L1.x + (L3.x - L1.x) * s3;
            const float a5 = L1.y + (L3.y - L1.y) * s3;
            const float a6 = L1.z + (L3.z - L1.z) * s3;
            const float a7 = L1.w + (L3.w - L1.w) * s3;
            const float b0 = a0 + (a4 - a0) * s2;
            const float b1 = a1 + (a5 - a1) * s2;
            const float b2 = a2 + (a6 - a2) * s2;
            const float b3 = a3 + (a7 - a3) * s2;
            const float c0 = b0 + (b2 - b0) * s1;
            const float c1 = b1 + (b3 - b1) * s1;
            const float res = c0 + (c1 - c0) * s0;
            const int row = bm0 + wr * 64 + mt * 16 + (lane >> 4) * 4 + r;
            out[(size_t)row * O_DIM + o] = res;
          }
        }
      }
    }
  }
}

// ---------------------------------------------------------------------------
extern "C" void kernel_launch(void* const* d_in, const int* in_sizes, int n_in,
                              void* d_out, int out_size, void* d_ws, size_t ws_size,
                              hipStream_t stream) {
  const float* x      = (const float*)d_in[0];  // (B, I)
  const float* logits = (const float*)d_in[1];  // (O, N, I)
  const float* lut    = (const float*)d_in[2];  // (O, 16)
  float* out          = (float*)d_out;          // (B, O)

  _Float16* wh = (_Float16*)d_ws;                                  // 8 MB
  _Float16* xh = (_Float16*)d_ws + (size_t)ON_DIM * I_DIM;         // 8 MB

  ltn_prep<<<2048, 256, 0, stream>>>(logits, x, wh, xh);
  dim3 grid(B_DIM / 128, ON_DIM / 128);
  ltn_gemm_lut<<<grid, 320, 0, stream>>>(xh, wh, lut, out);
}

// Round 7
// 142.913 us; speedup vs baseline: 1.4742x; 1.2902x over previous
//
#include <hip/hip_runtime.h>

#define B_DIM 4096
#define I_DIM 1024
#define O_DIM 1024
#define ON_DIM 4096      // O * N fan-in columns
#define TILE_HALFS 4096  // one 128(m) x 32(k) fp16 tile image = 8 KB
                         // image order: [kb8(4)][m(128)][j(8)] halfs

typedef _Float16 half8  __attribute__((ext_vector_type(8)));
typedef _Float16 half4_t __attribute__((ext_vector_type(4)));
typedef float    floatx4 __attribute__((ext_vector_type(4)));

// ---------------------------------------------------------------------------
// Prep: writes BOTH operands PRE-TILED in the GEMM's LDS-image order, so the
// GEMM's global_load_lds staging is fully contiguous (the R1-R5 staging was
// 64 lanes x 16B at 2KB stride = 64 scattered transactions/instr; FETCH_SIZE
// 41.4 MB vs 16.8 compulsory showed ~60% of every line wasted).
//  blocks [0,1024):    softmax of mapping_logits rows -> wt tiles (wave/row)
//  blocks [1024,2048): x fp32->fp16 tiling via LDS (coalesced in and out)
// ---------------------------------------------------------------------------
__global__ __launch_bounds__(256)
void ltn_prep(const float* __restrict__ logits, const float* __restrict__ x,
              _Float16* __restrict__ wt, _Float16* __restrict__ xt) {
  __shared__ _Float16 tile[TILE_HALFS];
  const int t = threadIdx.x, lane = t & 63, wv = t >> 6;
  if (blockIdx.x < 1024) {
    const int row = blockIdx.x * 4 + wv;       // ON row
    const float4* src = (const float4*)(logits + (size_t)row * I_DIM);
    float4 v[4];
#pragma unroll
    for (int j = 0; j < 4; j++) v[j] = src[j * 64 + lane];
    float m = -1e30f;
#pragma unroll
    for (int j = 0; j < 4; j++)
      m = fmaxf(m, fmaxf(fmaxf(v[j].x, v[j].y), fmaxf(v[j].z, v[j].w)));
#pragma unroll
    for (int off = 1; off < 64; off <<= 1) m = fmaxf(m, __shfl_xor(m, off));
    float e[16];
    float s = 0.0f;
#pragma unroll
    for (int j = 0; j < 4; j++) {
      e[4 * j + 0] = __expf(v[j].x - m);
      e[4 * j + 1] = __expf(v[j].y - m);
      e[4 * j + 2] = __expf(v[j].z - m);
      e[4 * j + 3] = __expf(v[j].w - m);
      s += (e[4 * j + 0] + e[4 * j + 1]) + (e[4 * j + 2] + e[4 * j + 3]);
    }
#pragma unroll
    for (int off = 1; off < 64; off <<= 1) s += __shfl_xor(s, off);
    const float inv = 1.0f / s;
    const int nb = row >> 7, nn = row & 127;
    _Float16* base = wt + (size_t)nb * 32 * TILE_HALFS + nn * 8;
#pragma unroll
    for (int jj = 0; jj < 4; jj++) {
      const int k0g  = jj * 256 + lane * 4;    // k within row
      const int kb32 = k0g >> 5;
      const int kb8  = (k0g >> 3) & 3;
      const int jr   = k0g & 7;                // 0 or 4
      half4_t h;
      h[0] = (_Float16)(e[4 * jj + 0] * inv);
      h[1] = (_Float16)(e[4 * jj + 1] * inv);
      h[2] = (_Float16)(e[4 * jj + 2] * inv);
      h[3] = (_Float16)(e[4 * jj + 3] * inv);
      *(half4_t*)(base + (size_t)kb32 * TILE_HALFS + kb8 * 1024 + jr) = h;
    }
  } else {
    const int bid = blockIdx.x - 1024;         // tile id
    const int mb = bid & 31, kt = bid >> 5;
    const int r8 = t >> 3, c4 = (t & 7) * 4;   // 8 threads cover 32 k-cols
    const int kb8 = c4 >> 3, jr = c4 & 7;
#pragma unroll
    for (int p = 0; p < 4; p++) {
      const int row = p * 32 + r8;
      const float4 v = *(const float4*)(
          x + (size_t)(mb * 128 + row) * I_DIM + kt * 32 + c4);
      half4_t h;
      h[0] = (_Float16)v.x; h[1] = (_Float16)v.y;
      h[2] = (_Float16)v.z; h[3] = (_Float16)v.w;
      *(half4_t*)&tile[kb8 * 1024 + row * 8 + jr] = h;
    }
    __syncthreads();
    _Float16* dst = xt + (size_t)(mb * 32 + kt) * TILE_HALFS;
    ((half8*)dst)[t]       = ((const half8*)tile)[t];
    ((half8*)dst)[256 + t] = ((const half8*)tile)[256 + t];
  }
}

// ---------------------------------------------------------------------------
// GEMM + sigmoid + 16-corner LUT. R1's proven 2-barrier structure, but the
// operands are pre-tiled: each global_load_lds now reads 1 KB CONTIGUOUS
// (vs 64 x 16B at 2KB stride) -> 4x fewer memory transactions, zero line
// waste. 128x128 block, 4 waves (2x2), each 64x64 = 4x4 MFMA 16x16x32 f16.
// ---------------------------------------------------------------------------
__global__ __launch_bounds__(256)
void ltn_gemm_lut(const _Float16* __restrict__ xt,   // [32][32][TILE_HALFS]
                  const _Float16* __restrict__ wt,   // [32][32][TILE_HALFS]
                  const float* __restrict__ lut,     // [O][16]
                  float* __restrict__ out) {         // [B][O]
  __shared__ _Float16 As[4][128][8];   // 8 KB, same image as the global tiles
  __shared__ _Float16 Bs[4][128][8];

  const int tid  = threadIdx.x;
  const int lane = tid & 63;
  const int wv   = tid >> 6;
  const int wr   = wv >> 1;      // wave row (0..1)
  const int wc   = wv & 1;       // wave col (0..1)
  const int mb   = blockIdx.x;
  const int nb   = blockIdx.y;
  const int bm0  = mb * 128;
  const int bn0  = nb * 128;
  const int fm   = lane & 15;
  const int kq   = lane >> 4;

  floatx4 acc[4][4];
#pragma unroll
  for (int i = 0; i < 4; i++)
#pragma unroll
    for (int j = 0; j < 4; j++) acc[i][j] = (floatx4)0.0f;

  for (int kt = 0; kt < 32; kt++) {
    const _Float16* tA = xt + (size_t)(mb * 32 + kt) * TILE_HALFS;
    const _Float16* tB = wt + (size_t)(nb * 32 + kt) * TILE_HALFS;
#pragma unroll
    for (int s = 0; s < 2; s++) {
      const int c = wv * 2 + s;                  // chunk 0..7 (1 KB each)
      const _Float16* gA = tA + c * 512 + lane * 8;   // contiguous 1 KB
      const _Float16* gB = tB + c * 512 + lane * 8;
      __builtin_amdgcn_global_load_lds(
          (const __attribute__((address_space(1))) void*)gA,
          (__attribute__((address_space(3))) void*)((char*)&As[0][0][0] + c * 1024),
          16, 0, 0);
      __builtin_amdgcn_global_load_lds(
          (const __attribute__((address_space(1))) void*)gB,
          (__attribute__((address_space(3))) void*)((char*)&Bs[0][0][0] + c * 1024),
          16, 0, 0);
    }
    __syncthreads();

    half8 af[4], bf[4];
#pragma unroll
    for (int f = 0; f < 4; f++) {
      af[f] = *(const half8*)&As[kq][wr * 64 + f * 16 + fm][0];
      bf[f] = *(const half8*)&Bs[kq][wc * 64 + f * 16 + fm][0];
    }
#pragma unroll
    for (int mt = 0; mt < 4; mt++)
#pragma unroll
      for (int nt = 0; nt < 4; nt++)
        acc[mt][nt] = __builtin_amdgcn_mfma_f32_16x16x32_f16(
            af[mt], bf[nt], acc[mt][nt], 0, 0, 0);
    __syncthreads();
  }

  // ---- fused epilogue: sigmoid -> gather 4 fan-in values -> LUT contraction
  // C/D layout: col = lane&15, row = (lane>>4)*4 + reg. The 4 n-values of one
  // o live in 4 consecutive lanes (same row, cols o*4..o*4+3).
#pragma unroll
  for (int nt = 0; nt < 4; nt++) {
    const int o = (bn0 + wc * 64 + nt * 16 + (lane & 15)) >> 2;
    const float4* lt4 = (const float4*)(lut + (size_t)o * 16);
    const float4 L0 = lt4[0], L1 = lt4[1], L2 = lt4[2], L3 = lt4[3];
#pragma unroll
    for (int mt = 0; mt < 4; mt++) {
#pragma unroll
      for (int r = 0; r < 4; r++) {
        const float v  = acc[mt][nt][r];
        const float sv = 1.0f / (1.0f + __expf(-v));
        const float s1 = __shfl_down(sv, 1);
        const float s2 = __shfl_down(sv, 2);
        const float s3 = __shfl_down(sv, 3);
        if ((lane & 3) == 0) {
          const float s0 = sv;
          const float a0 = L0.x + (L2.x - L0.x) * s3;
          const float a1 = L0.y + (L2.y - L0.y) * s3;
          const float a2 = L0.z + (L2.z - L0.z) * s3;
          const float a3 = L0.w + (L2.w - L0.w) * s3;
          const float a4 = L1.x + (L3.x - L1.x) * s3;
          const float a5 = L1.y + (L3.y - L1.y) * s3;
          const float a6 = L1.z + (L3.z - L1.z) * s3;
          const float a7 = L1.w + (L3.w - L1.w) * s3;
          const float b0 = a0 + (a4 - a0) * s2;
          const float b1 = a1 + (a5 - a1) * s2;
          const float b2 = a2 + (a6 - a2) * s2;
          const float b3 = a3 + (a7 - a3) * s2;
          const float c0 = b0 + (b2 - b0) * s1;
          const float c1 = b1 + (b3 - b1) * s1;
          const float res = c0 + (c1 - c0) * s0;
          const int row = bm0 + wr * 64 + mt * 16 + (lane >> 4) * 4 + r;
          out[(size_t)row * O_DIM + o] = res;
        }
      }
    }
  }
}

// ---------------------------------------------------------------------------
extern "C" void kernel_launch(void* const* d_in, const int* in_sizes, int n_in,
                              void* d_out, int out_size, void* d_ws, size_t ws_size,
                              hipStream_t stream) {
  const float* x      = (const float*)d_in[0];  // (B, I)
  const float* logits = (const float*)d_in[1];  // (O, N, I)
  const float* lut    = (const float*)d_in[2];  // (O, 16)
  float* out          = (float*)d_out;          // (B, O)

  _Float16* wt = (_Float16*)d_ws;                                  // 8 MB tiled
  _Float16* xt = (_Float16*)d_ws + (size_t)ON_DIM * I_DIM;         // 8 MB tiled

  ltn_prep<<<2048, 256, 0, stream>>>(logits, x, wt, xt);
  dim3 grid(B_DIM / 128, ON_DIM / 128);
  ltn_gemm_lut<<<grid, 256, 0, stream>>>(xt, wt, lut, out);
}

// Round 9
// 133.655 us; speedup vs baseline: 1.5764x; 1.0693x over previous
//
#include <hip/hip_runtime.h>

#define B_DIM 4096
#define I_DIM 1024
#define O_DIM 1024
#define ON_DIM 4096      // O * N fan-in columns
#define TILE_HALFS 4096  // one 128(m) x 32(k) fp16 tile image = 8 KB
                         // image order: [kb8(4)][m(128)][j(8)] halfs

typedef _Float16 half8  __attribute__((ext_vector_type(8)));
typedef _Float16 half4_t __attribute__((ext_vector_type(4)));
typedef float    floatx4 __attribute__((ext_vector_type(4)));

// ---------------------------------------------------------------------------
// Kernel A: per-row softmax stats (max, 1/sum) — one wave per row.
// ---------------------------------------------------------------------------
__global__ __launch_bounds__(256)
void ltn_stats(const float* __restrict__ logits, float2* __restrict__ stats) {
  const int t = threadIdx.x, lane = t & 63, wv = t >> 6;
  const int row = blockIdx.x * 4 + wv;
  const float4* src = (const float4*)(logits + (size_t)row * I_DIM);
  float4 v[4];
#pragma unroll
  for (int j = 0; j < 4; j++) v[j] = src[j * 64 + lane];
  float m = -1e30f;
#pragma unroll
  for (int j = 0; j < 4; j++)
    m = fmaxf(m, fmaxf(fmaxf(v[j].x, v[j].y), fmaxf(v[j].z, v[j].w)));
#pragma unroll
  for (int off = 1; off < 64; off <<= 1) m = fmaxf(m, __shfl_xor(m, off));
  float s = 0.0f;
#pragma unroll
  for (int j = 0; j < 4; j++) {
    s += __expf(v[j].x - m) + __expf(v[j].y - m)
       + __expf(v[j].z - m) + __expf(v[j].w - m);
  }
#pragma unroll
  for (int off = 1; off < 64; off <<= 1) s += __shfl_xor(s, off);
  if (lane == 0) stats[row] = make_float2(m, 1.0f / s);
}

// ---------------------------------------------------------------------------
// Kernel B: fully-coalesced tile writer (R7's wt path wrote 16B segments at
// 2KB stride — same transaction-rate pathology R7 fixed on the read side).
//  blocks [0,1024):    wt tile (nb,kb): softmax-normalize 128x32 logits block
//  blocks [1024,2048): xt tile (mb,kt): fp32->fp16 convert 128x32 x block
// Each thread: read 64B (4 float4) of one row-segment, write 2 half8 into
// the tile image — per-wave stores form two contiguous 512B runs.
// ---------------------------------------------------------------------------
__global__ __launch_bounds__(256)
void ltn_tile(const float* __restrict__ logits, const float* __restrict__ x,
              const float2* __restrict__ stats,
              _Float16* __restrict__ wt, _Float16* __restrict__ xt) {
  const int t  = threadIdx.x;
  const int nn = t >> 1;        // row within 128-tile
  const int hf = t & 1;         // which 16-k half of the 32-k tile
  if (blockIdx.x < 1024) {
    const int nb = blockIdx.x >> 5, kb = blockIdx.x & 31;
    const int row = nb * 128 + nn;
    const float2 st = stats[row];
    const float4* src = (const float4*)(logits + (size_t)row * I_DIM + kb * 32 + hf * 16);
    const float4 a = src[0], b = src[1], c = src[2], d = src[3];
    half8 h0, h1;
    h0[0] = (_Float16)(__expf(a.x - st.x) * st.y);
    h0[1] = (_Float16)(__expf(a.y - st.x) * st.y);
    h0[2] = (_Float16)(__expf(a.z - st.x) * st.y);
    h0[3] = (_Float16)(__expf(a.w - st.x) * st.y);
    h0[4] = (_Float16)(__expf(b.x - st.x) * st.y);
    h0[5] = (_Float16)(__expf(b.y - st.x) * st.y);
    h0[6] = (_Float16)(__expf(b.z - st.x) * st.y);
    h0[7] = (_Float16)(__expf(b.w - st.x) * st.y);
    h1[0] = (_Float16)(__expf(c.x - st.x) * st.y);
    h1[1] = (_Float16)(__expf(c.y - st.x) * st.y);
    h1[2] = (_Float16)(__expf(c.z - st.x) * st.y);
    h1[3] = (_Float16)(__expf(c.w - st.x) * st.y);
    h1[4] = (_Float16)(__expf(d.x - st.x) * st.y);
    h1[5] = (_Float16)(__expf(d.y - st.x) * st.y);
    h1[6] = (_Float16)(__expf(d.z - st.x) * st.y);
    h1[7] = (_Float16)(__expf(d.w - st.x) * st.y);
    _Float16* base = wt + ((size_t)nb * 32 + kb) * TILE_HALFS + (hf * 2) * 1024 + nn * 8;
    *(half8*)base = h0;
    *(half8*)(base + 1024) = h1;
  } else {
    const int bid = blockIdx.x - 1024;
    const int mb = bid >> 5, kt = bid & 31;
    const int row = mb * 128 + nn;
    const float4* src = (const float4*)(x + (size_t)row * I_DIM + kt * 32 + hf * 16);
    const float4 a = src[0], b = src[1], c = src[2], d = src[3];
    half8 h0, h1;
    h0[0] = (_Float16)a.x; h0[1] = (_Float16)a.y; h0[2] = (_Float16)a.z; h0[3] = (_Float16)a.w;
    h0[4] = (_Float16)b.x; h0[5] = (_Float16)b.y; h0[6] = (_Float16)b.z; h0[7] = (_Float16)b.w;
    h1[0] = (_Float16)c.x; h1[1] = (_Float16)c.y; h1[2] = (_Float16)c.z; h1[3] = (_Float16)c.w;
    h1[4] = (_Float16)d.x; h1[5] = (_Float16)d.y; h1[6] = (_Float16)d.z; h1[7] = (_Float16)d.w;
    _Float16* base = xt + ((size_t)mb * 32 + kt) * TILE_HALFS + (hf * 2) * 1024 + nn * 8;
    *(half8*)base = h0;
    *(half8*)(base + 1024) = h1;
  }
}

// ---------------------------------------------------------------------------
// GEMM + sigmoid + 16-corner LUT. 256x256 block tile (8 waves, 4x2), BK=32,
// double-buffered contiguous staging. Rationale: staging sustains ~30 B/cyc/CU
// (R7); 128-tile needs 128 B/cyc for full MFMA (hence 20% MfmaUtil), 256-tile
// needs only 32 B/cyc. Grid 16x16 = 256 blocks = exactly 1/CU (no tail).
// Prefetch is issued right after the barrier, so the next barrier's vmcnt(0)
// drains loads that had the full ~1100-cyc compute phase in flight.
// ---------------------------------------------------------------------------
__global__ __launch_bounds__(512, 2)
void ltn_gemm_lut(const _Float16* __restrict__ xt,   // tiles [32*32][TILE_HALFS]
                  const _Float16* __restrict__ wt,
                  const float* __restrict__ lut,     // [O][16]
                  float* __restrict__ out) {         // [B][O]
  __shared__ _Float16 As[2][2][4][128][8];   // [buf][mtile][kb8][m][j] 2x16KB
  __shared__ _Float16 Bs[2][2][4][128][8];

  const int tid  = threadIdx.x;
  const int lane = tid & 63;
  const int wv   = tid >> 6;     // 0..7
  const int wr   = wv >> 1;      // row-wave 0..3  (64 rows each)
  const int wc   = wv & 1;       // col-wave 0..1  (128 cols each)
  const int mb   = blockIdx.x;   // 0..15
  const int nb   = blockIdx.y;   // 0..15
  const int fm   = lane & 15;
  const int kq   = lane >> 4;

  const size_t baseA = (size_t)(mb * 2) * 32 * TILE_HALFS;
  const size_t baseB = (size_t)(nb * 2) * 32 * TILE_HALFS;

  floatx4 acc[4][8];
#pragma unroll
  for (int i = 0; i < 4; i++)
#pragma unroll
    for (int j = 0; j < 8; j++) acc[i][j] = (floatx4)0.0f;

  // 32 chunks of 1KB per buffer (16 A + 16 B); 4 GLLs per wave.
  auto stage = [&](int buf, int kt) {
#pragma unroll
    for (int s = 0; s < 4; s++) {
      const int c   = wv * 4 + s;        // 0..31, wave-uniform split
      const int cc  = c & 15;            // chunk within matrix
      const int tl  = cc >> 3;           // which 128-row tile (0/1)
      const int sub = cc & 7;            // 1KB sub-chunk
      const _Float16* g;
      char* l;
      if (c < 16) {
        g = xt + baseA + (size_t)(tl * 32 + kt) * TILE_HALFS + sub * 512 + lane * 8;
        l = (char*)&As[buf][0][0][0][0] + cc * 1024;
      } else {
        g = wt + baseB + (size_t)(tl * 32 + kt) * TILE_HALFS + sub * 512 + lane * 8;
        l = (char*)&Bs[buf][0][0][0][0] + cc * 1024;
      }
      __builtin_amdgcn_global_load_lds(
          (const __attribute__((address_space(1))) void*)g,
          (__attribute__((address_space(3))) void*)l, 16, 0, 0);
    }
  };

  auto compute = [&](int buf) {
    half8 af[4], bf[8];
#pragma unroll
    for (int f = 0; f < 4; f++)
      af[f] = *(const half8*)&As[buf][wr >> 1][kq][(wr & 1) * 64 + f * 16 + fm][0];
#pragma unroll
    for (int g = 0; g < 8; g++)
      bf[g] = *(const half8*)&Bs[buf][wc][kq][g * 16 + fm][0];
#pragma unroll
    for (int mt = 0; mt < 4; mt++)
#pragma unroll
      for (int nt = 0; nt < 8; nt++)
        acc[mt][nt] = __builtin_amdgcn_mfma_f32_16x16x32_f16(
            af[mt], bf[nt], acc[mt][nt], 0, 0, 0);
  };

  stage(0, 0);
  int buf = 0;
  for (int kt = 0; kt < 32; kt++) {
    __syncthreads();                     // waits cur buf; prefetch had full prev compute in flight
    if (kt + 1 < 32) stage(buf ^ 1, kt + 1);
    compute(buf);
    buf ^= 1;
  }

  // ---- fused epilogue: sigmoid -> gather 4 fan-in values -> LUT contraction
  // C/D layout: col = lane&15, row = (lane>>4)*4 + reg. The 4 n-values of one
  // o live in 4 consecutive lanes.
#pragma unroll
  for (int nt = 0; nt < 8; nt++) {
    const int o = (nb * 256 + wc * 128 + nt * 16 + fm) >> 2;
    const float4* lt4 = (const float4*)(lut + (size_t)o * 16);
    const float4 L0 = lt4[0], L1 = lt4[1], L2 = lt4[2], L3 = lt4[3];
#pragma unroll
    for (int mt = 0; mt < 4; mt++) {
#pragma unroll
      for (int r = 0; r < 4; r++) {
        const float v  = acc[mt][nt][r];
        const float sv = 1.0f / (1.0f + __expf(-v));
        const float s1 = __shfl_down(sv, 1);
        const float s2 = __shfl_down(sv, 2);
        const float s3 = __shfl_down(sv, 3);
        if ((lane & 3) == 0) {
          const float s0 = sv;
          const float a0 = L0.x + (L2.x - L0.x) * s3;
          const float a1 = L0.y + (L2.y - L0.y) * s3;
          const float a2 = L0.z + (L2.z - L0.z) * s3;
          const float a3 = L0.w + (L2.w - L0.w) * s3;
          const float a4 = L1.x + (L3.x - L1.x) * s3;
          const float a5 = L1.y + (L3.y - L1.y) * s3;
          const float a6 = L1.z + (L3.z - L1.z) * s3;
          const float a7 = L1.w + (L3.w - L1.w) * s3;
          const float b0 = a0 + (a4 - a0) * s2;
          const float b1 = a1 + (a5 - a1) * s2;
          const float b2 = a2 + (a6 - a2) * s2;
          const float b3 = a3 + (a7 - a3) * s2;
          const float c0 = b0 + (b2 - b0) * s1;
          const float c1 = b1 + (b3 - b1) * s1;
          const float res = c0 + (c1 - c0) * s0;
          const int row = mb * 256 + wr * 64 + mt * 16 + (lane >> 4) * 4 + r;
          out[(size_t)row * O_DIM + o] = res;
        }
      }
    }
  }
}

// ---------------------------------------------------------------------------
extern "C" void kernel_launch(void* const* d_in, const int* in_sizes, int n_in,
                              void* d_out, int out_size, void* d_ws, size_t ws_size,
                              hipStream_t stream) {
  const float* x      = (const float*)d_in[0];  // (B, I)
  const float* logits = (const float*)d_in[1];  // (O, N, I)
  const float* lut    = (const float*)d_in[2];  // (O, 16)
  float* out          = (float*)d_out;          // (B, O)

  _Float16* wt = (_Float16*)d_ws;                                  // 8 MB tiled
  _Float16* xt = (_Float16*)d_ws + (size_t)ON_DIM * I_DIM;         // 8 MB tiled
  // stats scratch parked in d_out (32 KB); GEMM fully overwrites d_out later.
  float2* stats = (float2*)d_out;

  ltn_stats<<<1024, 256, 0, stream>>>(logits, stats);
  ltn_tile<<<2048, 256, 0, stream>>>(logits, x, stats, wt, xt);
  dim3 grid(16, 16);
  ltn_gemm_lut<<<grid, 512, 0, stream>>>(xt, wt, lut, out);
}